// Round 1
// baseline (278.431 us; speedup 1.0000x reference)
//
#include <hip/hip_runtime.h>
#include <math.h>

// Problem constants: B=4, C=64, H=W=128, OUTC=64, KS=3, PAD=1, N=9 taps, 18 offset ch.
//
// ws layout (floats):
//   x_t     [4][128][128][64]   NHWC transpose of x          @ 0        (16 MB)
//   convw_t [9][64][64]         conv_w as [n][c][o]          @ 4194304  (147 KB)
//   pw_t    [576][20]           p_w as [k=(uv*64+c)][n pad20]@ 4231168  (46 KB)
//   offs    [4][128][128][18]   offset conv output, NHWC-ish @ 4242688  (4.7 MB)
static const size_t OFF_XT  = 0;
static const size_t OFF_CWT = 4194304;
static const size_t OFF_PWT = OFF_CWT + 36864;
static const size_t OFF_OFS = OFF_PWT + 11520;
static const size_t WS_FLOATS = OFF_OFS + 1179648;

// ---------------- K1a: x NCHW -> NHWC ----------------
__global__ __launch_bounds__(256) void k_transpose_x(const float* __restrict__ x,
                                                     float* __restrict__ x_t) {
    __shared__ float t[64][129];
    int b = blockIdx.x >> 7;
    int i = blockIdx.x & 127;
    for (int idx = threadIdx.x; idx < 64 * 128; idx += 256) {
        int c = idx >> 7, j = idx & 127;
        t[c][j] = x[(((size_t)(b * 64 + c) * 128 + i) << 7) + j];
    }
    __syncthreads();
    float* dst = x_t + ((size_t)(b * 128 + i)) * 128 * 64;
    for (int idx = threadIdx.x; idx < 64 * 128; idx += 256) {
        int j = idx >> 6, c = idx & 63;
        dst[idx] = t[c][j];
    }
}

// ---------------- K1b: weight transposes ----------------
__global__ __launch_bounds__(256) void k_small_t(const float* __restrict__ conv_w,
                                                 const float* __restrict__ p_w,
                                                 float* __restrict__ cwt,
                                                 float* __restrict__ pwt) {
    int tid = blockIdx.x * 256 + threadIdx.x;
    if (tid < 36864) {  // cwt[(n*64+c)*64+o] = conv_w[(o*64+c)*9+n]
        int o = tid & 63, c = (tid >> 6) & 63, n = tid >> 12;
        cwt[tid] = conv_w[(o * 64 + c) * 9 + n];
    }
    if (tid < 11520) {  // pwt[k*20+n] = p_w[(n*64+c)*9+uv], k = uv*64+c
        int n = tid % 20, k = tid / 20;
        int c = k & 63, uv = k >> 6;
        pwt[tid] = (n < 18) ? p_w[(n * 64 + c) * 9 + uv] : 0.f;
    }
}

// ---------------- K2: offset conv (3x3, pad 1, 18 out ch) ----------------
// Block: 64 pixels of one row (b, i, j0..j0+63); 256 thr = (p in 0..63, cq in 0..3).
// Each thread accumulates acc[18] over its 16 channels; 4-way LDS reduce.
__global__ __launch_bounds__(256) void k_offset(const float* __restrict__ x_t,
                                                const float* __restrict__ pw_t,
                                                const float* __restrict__ p_b,
                                                float* __restrict__ offs_out) {
    __shared__ float smem[3 * 64 * 66];  // xs[u][c][col66]; later reused as red[4][64][20]
    int blk = blockIdx.x;
    int b = blk >> 8;
    int i = (blk >> 1) & 127;
    int j0 = (blk & 1) * 64;

    for (int idx = threadIdx.x; idx < 3 * 66 * 64; idx += 256) {
        int u = idx / (66 * 64);
        int rem = idx - u * 66 * 64;
        int col = rem >> 6;
        int c = rem & 63;
        int row = i - 1 + u;
        int jj = j0 - 1 + col;
        float v = 0.f;
        if ((unsigned)row < 128u && (unsigned)jj < 128u)
            v = x_t[(((size_t)((b * 128 + row) * 128 + jj)) << 6) + c];
        smem[(u * 64 + c) * 66 + col] = v;
    }
    __syncthreads();

    int p = threadIdx.x & 63;
    int cq = threadIdx.x >> 6;
    int c0 = cq * 16;
    float acc[18];
#pragma unroll
    for (int k = 0; k < 18; ++k) acc[k] = 0.f;

    for (int u = 0; u < 3; ++u) {
        for (int v = 0; v < 3; ++v) {
            const float* xrow = smem + (u * 64 + c0) * 66 + p + v;
            const float* pwb = pw_t + ((u * 3 + v) * 64 + c0) * 20;
#pragma unroll 4
            for (int cc = 0; cc < 16; ++cc) {
                float xv = xrow[cc * 66];
                const float* pk = pwb + cc * 20;
                float4 q0 = *(const float4*)(pk + 0);
                float4 q1 = *(const float4*)(pk + 4);
                float4 q2 = *(const float4*)(pk + 8);
                float4 q3 = *(const float4*)(pk + 12);
                float2 q4 = *(const float2*)(pk + 16);
                acc[0]  = fmaf(xv, q0.x, acc[0]);
                acc[1]  = fmaf(xv, q0.y, acc[1]);
                acc[2]  = fmaf(xv, q0.z, acc[2]);
                acc[3]  = fmaf(xv, q0.w, acc[3]);
                acc[4]  = fmaf(xv, q1.x, acc[4]);
                acc[5]  = fmaf(xv, q1.y, acc[5]);
                acc[6]  = fmaf(xv, q1.z, acc[6]);
                acc[7]  = fmaf(xv, q1.w, acc[7]);
                acc[8]  = fmaf(xv, q2.x, acc[8]);
                acc[9]  = fmaf(xv, q2.y, acc[9]);
                acc[10] = fmaf(xv, q2.z, acc[10]);
                acc[11] = fmaf(xv, q2.w, acc[11]);
                acc[12] = fmaf(xv, q3.x, acc[12]);
                acc[13] = fmaf(xv, q3.y, acc[13]);
                acc[14] = fmaf(xv, q3.z, acc[14]);
                acc[15] = fmaf(xv, q3.w, acc[15]);
                acc[16] = fmaf(xv, q4.x, acc[16]);
                acc[17] = fmaf(xv, q4.y, acc[17]);
            }
        }
    }
    __syncthreads();  // done reading xs; reuse smem as red[4][64][20]
    float* rr = smem + (cq * 64 + p) * 20;
#pragma unroll
    for (int k = 0; k < 18; ++k) rr[k] = acc[k];
    __syncthreads();

    size_t obase = ((size_t)((b * 128 + i) * 128 + j0)) * 18;
    for (int item = threadIdx.x; item < 64 * 18; item += 256) {
        int pp = item / 18;
        int nn = item - pp * 18;
        float s = smem[pp * 20 + nn] + smem[1280 + pp * 20 + nn] +
                  smem[2560 + pp * 20 + nn] + smem[3840 + pp * 20 + nn] + p_b[nn];
        offs_out[obase + item] = s;
    }
}

// ---------------- K3: fused bilinear sampling + 576x64 GEMM ----------------
// Block: 32 pixels (one row segment). Loop over n=0..8:
//   A: 32 threads compute 4 corner bases + bilinear weights
//   B: 256 threads gather xoff[32][64] (coalesced 256B per corner)
//   C: 4 waves, lane=o, 8 pixels/lane, FMA over 64 channels
__global__ __launch_bounds__(256) void k_fused(const float* __restrict__ x_t,
                                               const float* __restrict__ offs_in,
                                               const float* __restrict__ convw_t,
                                               const float* __restrict__ conv_b,
                                               float* __restrict__ out) {
    __shared__ float offs[576];     // [32][18]
    __shared__ float cw[4096];      // [c][o] for current n
    __shared__ float xoff[2112];    // [32][64] sampling; [64][33] epilogue
    __shared__ int idxl[4 * 32];
    __shared__ float wl[4 * 32];

    int pix0 = blockIdx.x * 32;
    int b = pix0 >> 14;
    int rem = pix0 & 16383;
    int i = rem >> 7;
    int j0 = rem & 127;
    int tid = threadIdx.x;

    const float* ob = offs_in + (size_t)pix0 * 18;
    for (int idx = tid; idx < 576; idx += 256) offs[idx] = ob[idx];
    __syncthreads();

    float acc[8];
#pragma unroll
    for (int k = 0; k < 8; ++k) acc[k] = 0.f;

    int o = tid & 63;
    int wv = tid >> 6;
    int pbase = wv * 8;

    for (int n = 0; n < 9; ++n) {
        // stage conv_w chunk [64c][64o] for this tap
        {
            const float4* src = (const float4*)(convw_t + n * 4096);
            float4* dst4 = (float4*)cw;
            for (int idx = tid; idx < 1024; idx += 256) dst4[idx] = src[idx];
        }
        // phase A: bilinear geometry for 32 pixels
        if (tid < 32) {
            int p = tid;
            float ox = offs[p * 18 + n];
            float oy = offs[p * 18 + 9 + n];
            float px = ox + (float)(i + 1) + (float)(n / 3 - 1);
            float py = oy + (float)(j0 + p + 1) + (float)(n % 3 - 1);
            float fx = floorf(px), fy = floorf(py);
            float qlx = fminf(fmaxf(fx, 0.f), 129.f);
            float qrx = fminf(fmaxf(fx + 1.f, 0.f), 129.f);
            float qly = fminf(fmaxf(fy, 0.f), 129.f);
            float qry = fminf(fmaxf(fy + 1.f, 0.f), 129.f);
            float pxc = fminf(fmaxf(px, 0.f), 129.f);
            float pyc = fminf(fmaxf(py, 0.f), 129.f);
            float ax = 1.f + qlx - pxc;  // (1 + (qltx - pxc))
            float bx = 1.f - qrx + pxc;  // (1 - (qrbx - pxc))
            float ay = 1.f + qly - pyc;
            float by = 1.f - qry + pyc;
            int rlx = (int)qlx - 1, rrx = (int)qrx - 1;
            int rly = (int)qly - 1, rry = (int)qry - 1;
            int bb = b * 128;
            idxl[0 * 32 + p] = ((unsigned)rlx < 128u && (unsigned)rly < 128u)
                                   ? (((bb + rlx) * 128 + rly) << 6) : -1;
            wl[0 * 32 + p] = ax * ay;  // glt
            idxl[1 * 32 + p] = ((unsigned)rrx < 128u && (unsigned)rry < 128u)
                                   ? (((bb + rrx) * 128 + rry) << 6) : -1;
            wl[1 * 32 + p] = bx * by;  // grb
            idxl[2 * 32 + p] = ((unsigned)rlx < 128u && (unsigned)rry < 128u)
                                   ? (((bb + rlx) * 128 + rry) << 6) : -1;
            wl[2 * 32 + p] = ax * by;  // glb
            idxl[3 * 32 + p] = ((unsigned)rrx < 128u && (unsigned)rly < 128u)
                                   ? (((bb + rrx) * 128 + rly) << 6) : -1;
            wl[3 * 32 + p] = bx * ay;  // grt
        }
        __syncthreads();

        // phase B: gather — thread (wv, c=o): 8 pixels
        {
            int c = o;
#pragma unroll
            for (int pp = 0; pp < 8; ++pp) {
                int p = pbase + pp;
                float v = 0.f;
#pragma unroll
                for (int k = 0; k < 4; ++k) {
                    int base = idxl[k * 32 + p];
                    float wk = wl[k * 32 + p];
                    float xv = (base >= 0) ? x_t[base + c] : 0.f;
                    v = fmaf(wk, xv, v);
                }
                xoff[p * 64 + c] = v;
            }
        }
        __syncthreads();

        // phase C: GEMM accumulate — lane=o, 8 pixels
#pragma unroll 4
        for (int c4 = 0; c4 < 16; ++c4) {
            float w0 = cw[(c4 * 4 + 0) * 64 + o];
            float w1 = cw[(c4 * 4 + 1) * 64 + o];
            float w2 = cw[(c4 * 4 + 2) * 64 + o];
            float w3 = cw[(c4 * 4 + 3) * 64 + o];
#pragma unroll
            for (int pp = 0; pp < 8; ++pp) {
                const float4 xv = *(const float4*)(xoff + (pbase + pp) * 64 + c4 * 4);
                acc[pp] = fmaf(xv.x, w0, acc[pp]);
                acc[pp] = fmaf(xv.y, w1, acc[pp]);
                acc[pp] = fmaf(xv.z, w2, acc[pp]);
                acc[pp] = fmaf(xv.w, w3, acc[pp]);
            }
        }
        __syncthreads();
    }

    // epilogue: transpose acc via LDS so stores are j-coalesced
#pragma unroll
    for (int pp = 0; pp < 8; ++pp) xoff[o * 33 + pbase + pp] = acc[pp];
    __syncthreads();
    for (int idx = tid; idx < 2048; idx += 256) {
        int oo = idx >> 5;
        int p = idx & 31;
        out[(((size_t)(b * 64 + oo) * 128 + i) << 7) + j0 + p] = xoff[oo * 33 + p] + conv_b[oo];
    }
}

extern "C" void kernel_launch(void* const* d_in, const int* in_sizes, int n_in,
                              void* d_out, int out_size, void* d_ws, size_t ws_size,
                              hipStream_t stream) {
    const float* x = (const float*)d_in[0];
    const float* p_w = (const float*)d_in[1];
    const float* p_b = (const float*)d_in[2];
    const float* conv_w = (const float*)d_in[3];
    const float* conv_b = (const float*)d_in[4];
    float* out = (float*)d_out;
    float* ws = (float*)d_ws;

    if (ws_size < WS_FLOATS * sizeof(float)) return;  // need ~21.7 MB scratch

    float* x_t = ws + OFF_XT;
    float* cwt = ws + OFF_CWT;
    float* pwt = ws + OFF_PWT;
    float* ofs = ws + OFF_OFS;

    k_transpose_x<<<512, 256, 0, stream>>>(x, x_t);
    k_small_t<<<144, 256, 0, stream>>>(conv_w, p_w, cwt, pwt);
    k_offset<<<1024, 256, 0, stream>>>(x_t, pwt, p_b, ofs);
    k_fused<<<2048, 256, 0, stream>>>(x_t, ofs, cwt, conv_b, out);
}

// Round 2
// 106.806 us; speedup vs baseline: 2.6069x; 2.6069x over previous
//
#include <hip/hip_runtime.h>
#include <math.h>

// B=4, C=64, H=W=128, OUTC=64, KS=3, taps N=9, K = 9*64 = 576.
// ws layout (bytes):
//   x_t  bf16 [4][128][128][64]  @ 0         (8 MB)   NHWC
//   cwt  bf16 [64][576]          @ 8388608   (72 KB)  cwt[o][n*64+c] = conv_w[o][c][n]
//   pwt  bf16 [32][576]          @ 8462336   (36 KB)  pwt[n'][n*64+c] = p_w[n'][c][n], rows 18..31 = 0
#define CWT_OFF 8388608
#define PWT_OFF 8462336

typedef __attribute__((ext_vector_type(8))) short short8;
typedef __attribute__((ext_vector_type(8))) unsigned short ushort8;
typedef __attribute__((ext_vector_type(4))) float f32x4;

__device__ inline float bf2f(unsigned short u) {
    union { unsigned int i; float f; } c; c.i = ((unsigned int)u) << 16; return c.f;
}
__device__ inline unsigned short f2bf(float f) {
    union { float f; unsigned int i; } c; c.f = f;
    return (unsigned short)((c.i + 0x7FFFu + ((c.i >> 16) & 1u)) >> 16);
}

// ---------------- prep: x NCHW f32 -> NHWC bf16 ----------------
__global__ __launch_bounds__(256) void k_prep_x(const float* __restrict__ x,
                                                unsigned int* __restrict__ x_t_u32) {
    __shared__ float t[64][129];
    int b = blockIdx.x >> 7;
    int i = blockIdx.x & 127;
    for (int idx = threadIdx.x; idx < 64 * 128; idx += 256) {
        int c = idx >> 7, j = idx & 127;
        t[c][j] = x[(((size_t)(b * 64 + c) * 128 + i) << 7) + j];
    }
    __syncthreads();
    unsigned int* dst = x_t_u32 + ((size_t)(b * 128 + i)) * 128 * 32;  // 32 u32 per pixel
    for (int idx2 = threadIdx.x; idx2 < 4096; idx2 += 256) {
        int j = idx2 >> 5, c2 = idx2 & 31;
        unsigned int lo = f2bf(t[2 * c2][j]);
        unsigned int hi = f2bf(t[2 * c2 + 1][j]);
        dst[idx2] = lo | (hi << 16);
    }
}

// ---------------- prep: weights -> bf16 transposed ----------------
__global__ __launch_bounds__(256) void k_prep_w(const float* __restrict__ conv_w,
                                                const float* __restrict__ p_w,
                                                unsigned short* __restrict__ cwt,
                                                unsigned short* __restrict__ pwt) {
    int tid = blockIdx.x * 256 + threadIdx.x;
    if (tid < 36864) {  // cwt[o*576 + n*64 + c] = conv_w[(o*64+c)*9 + n]
        int o = tid / 576, k = tid - o * 576;
        int n = k >> 6, c = k & 63;
        cwt[tid] = f2bf(conv_w[(o * 64 + c) * 9 + n]);
    } else if (tid < 36864 + 18432) {  // pwt[np*576 + n*64 + c]
        int t = tid - 36864;
        int np = t / 576, k = t - np * 576;
        int n = k >> 6, c = k & 63;
        pwt[t] = (np < 18) ? f2bf(p_w[(np * 64 + c) * 9 + n]) : (unsigned short)0;
    }
}

// ---------------- fused: offset-conv MFMA + geometry + bilinear + main MFMA ----------------
// Block = 64 pixels (b, i, j0..j0+63). 4 waves; wave wv owns pixels wv*16..wv*16+15.
// MFMA 16x16x32 bf16. A frag: m=lane&15, k=8*(lane>>4)+e. B frag: n=lane&15, same k.
// D: n=lane&15, m=4*(lane>>4)+reg.
__global__ __launch_bounds__(256) void k_fused(const unsigned short* __restrict__ x_t,
                                               const unsigned short* __restrict__ cwt,
                                               const unsigned short* __restrict__ pwt,
                                               const float* __restrict__ p_b,
                                               const float* __restrict__ conv_b,
                                               float* __restrict__ out) {
    __shared__ float S[5760];
    float* offs = S;                       // [64][18] f32
    int* igeom = (int*)(S + 1152);         // [9][4][64]
    float* wgeom = S + 3456;               // [9][4][64]
    float* ep = S + 1152;                  // [64][65] epilogue (reuses geom region)

    int bid = blockIdx.x;
    int b = bid >> 8;
    int i = (bid >> 1) & 127;
    int j0 = (bid & 1) << 6;

    int tid = threadIdx.x;
    int wv = tid >> 6;
    int lane = tid & 63;
    int r15 = lane & 15;
    int g = lane >> 4;
    int c0 = g << 3;          // 8*(lane>>4)
    int pl = wv * 16 + r15;   // this lane's A-row pixel (within block)

    // ---- phase 1: offset conv via MFMA, A direct from x_t ----
    f32x4 aco[2];
#pragma unroll
    for (int nb = 0; nb < 2; ++nb) aco[nb] = (f32x4)0.f;

    for (int n = 0; n < 9; ++n) {
        int du = n / 3 - 1, dv = n % 3 - 1;
        int row = i + du;
        int col = j0 + pl + dv;
        bool valid = ((unsigned)row < 128u) && ((unsigned)col < 128u);
        ushort8 v0 = (ushort8)(unsigned short)0, v1 = v0;
        if (valid) {
            const unsigned short* ap = x_t + (((size_t)((b * 128 + row) * 128 + col)) << 6);
            v0 = *(const ushort8*)(ap + c0);
            v1 = *(const ushort8*)(ap + c0 + 32);
        }
        short8 a0 = __builtin_bit_cast(short8, v0);
        short8 a1 = __builtin_bit_cast(short8, v1);
#pragma unroll
        for (int nb = 0; nb < 2; ++nb) {
            const unsigned short* bp = pwt + (nb * 16 + r15) * 576 + n * 64 + c0;
            short8 b0 = *(const short8*)bp;
            short8 b1 = *(const short8*)(bp + 32);
            aco[nb] = __builtin_amdgcn_mfma_f32_16x16x32_bf16(a0, b0, aco[nb], 0, 0, 0);
            aco[nb] = __builtin_amdgcn_mfma_f32_16x16x32_bf16(a1, b1, aco[nb], 0, 0, 0);
        }
    }
    // write offs[pix][n'] = acc + bias
#pragma unroll
    for (int nb = 0; nb < 2; ++nb) {
        int np = nb * 16 + r15;
        if (np < 18) {
            float bias = p_b[np];
#pragma unroll
            for (int rr = 0; rr < 4; ++rr) {
                int pix = wv * 16 + g * 4 + rr;
                offs[pix * 18 + np] = aco[nb][rr] + bias;
            }
        }
    }
    __syncthreads();

    // ---- phase 2: bilinear geometry per (pixel, tap) ----
    for (int t = tid; t < 576; t += 256) {
        int p = t / 9;
        int n = t - p * 9;
        float ox = offs[p * 18 + n];
        float oy = offs[p * 18 + 9 + n];
        float px = ox + (float)(i + 1) + (float)(n / 3 - 1);
        float py = oy + (float)(j0 + p + 1) + (float)(n % 3 - 1);
        float fx = floorf(px), fy = floorf(py);
        float qlx = fminf(fmaxf(fx, 0.f), 129.f);
        float qrx = fminf(fmaxf(fx + 1.f, 0.f), 129.f);
        float qly = fminf(fmaxf(fy, 0.f), 129.f);
        float qry = fminf(fmaxf(fy + 1.f, 0.f), 129.f);
        float pxc = fminf(fmaxf(px, 0.f), 129.f);
        float pyc = fminf(fmaxf(py, 0.f), 129.f);
        float ax = 1.f + qlx - pxc;
        float bx = 1.f - qrx + pxc;
        float ay = 1.f + qly - pyc;
        float by = 1.f - qry + pyc;
        int rlx = (int)qlx - 1, rrx = (int)qrx - 1;
        int rly = (int)qly - 1, rry = (int)qry - 1;
        int bb = b * 128;
        int base;
        base = ((unsigned)rlx < 128u && (unsigned)rly < 128u) ? (((bb + rlx) * 128 + rly) << 6) : -1;
        igeom[(n * 4 + 0) * 64 + p] = base;  wgeom[(n * 4 + 0) * 64 + p] = ax * ay;
        base = ((unsigned)rrx < 128u && (unsigned)rry < 128u) ? (((bb + rrx) * 128 + rry) << 6) : -1;
        igeom[(n * 4 + 1) * 64 + p] = base;  wgeom[(n * 4 + 1) * 64 + p] = bx * by;
        base = ((unsigned)rlx < 128u && (unsigned)rry < 128u) ? (((bb + rlx) * 128 + rry) << 6) : -1;
        igeom[(n * 4 + 2) * 64 + p] = base;  wgeom[(n * 4 + 2) * 64 + p] = ax * by;
        base = ((unsigned)rrx < 128u && (unsigned)rly < 128u) ? (((bb + rrx) * 128 + rly) << 6) : -1;
        igeom[(n * 4 + 3) * 64 + p] = base;  wgeom[(n * 4 + 3) * 64 + p] = bx * ay;
    }
    __syncthreads();

    // ---- phase 3: main conv — build bilinear A-frags in registers, MFMA over 4 n-blocks ----
    f32x4 acc[4];
#pragma unroll
    for (int nb = 0; nb < 4; ++nb) acc[nb] = (f32x4)0.f;

    for (int n = 0; n < 9; ++n) {
        int base_[4];
        float w_[4];
#pragma unroll
        for (int k = 0; k < 4; ++k) {
            base_[k] = igeom[(n * 4 + k) * 64 + pl];
            w_[k] = wgeom[(n * 4 + k) * 64 + pl];
        }
        float a0[8], a1[8];
#pragma unroll
        for (int e = 0; e < 8; ++e) { a0[e] = 0.f; a1[e] = 0.f; }
#pragma unroll
        for (int k = 0; k < 4; ++k) {
            if (base_[k] >= 0) {
                const unsigned short* ap = x_t + base_[k] + c0;
                ushort8 u0 = *(const ushort8*)ap;
                ushort8 u1 = *(const ushort8*)(ap + 32);
                float wk = w_[k];
#pragma unroll
                for (int e = 0; e < 8; ++e) {
                    a0[e] = fmaf(wk, bf2f(u0[e]), a0[e]);
                    a1[e] = fmaf(wk, bf2f(u1[e]), a1[e]);
                }
            }
        }
        short8 fa0, fa1;
#pragma unroll
        for (int e = 0; e < 8; ++e) {
            fa0[e] = (short)f2bf(a0[e]);
            fa1[e] = (short)f2bf(a1[e]);
        }
#pragma unroll
        for (int nb = 0; nb < 4; ++nb) {
            const unsigned short* bp = cwt + (nb * 16 + r15) * 576 + n * 64 + c0;
            short8 b0 = *(const short8*)bp;
            short8 b1 = *(const short8*)(bp + 32);
            acc[nb] = __builtin_amdgcn_mfma_f32_16x16x32_bf16(fa0, b0, acc[nb], 0, 0, 0);
            acc[nb] = __builtin_amdgcn_mfma_f32_16x16x32_bf16(fa1, b1, acc[nb], 0, 0, 0);
        }
    }
    __syncthreads();  // geom region now reusable as ep

    // ---- epilogue: LDS transpose, coalesced NCHW store ----
#pragma unroll
    for (int nb = 0; nb < 4; ++nb) {
        int o = nb * 16 + r15;
#pragma unroll
        for (int rr = 0; rr < 4; ++rr) {
            int pix = wv * 16 + g * 4 + rr;
            ep[o * 65 + pix] = acc[nb][rr];
        }
    }
    __syncthreads();
    for (int t = tid; t < 4096; t += 256) {
        int o = t >> 6;
        int p = t & 63;
        out[(((size_t)(b * 64 + o)) << 14) + (i << 7) + j0 + p] = ep[o * 65 + p] + conv_b[o];
    }
}

extern "C" void kernel_launch(void* const* d_in, const int* in_sizes, int n_in,
                              void* d_out, int out_size, void* d_ws, size_t ws_size,
                              hipStream_t stream) {
    const float* x = (const float*)d_in[0];
    const float* p_w = (const float*)d_in[1];
    const float* p_b = (const float*)d_in[2];
    const float* conv_w = (const float*)d_in[3];
    const float* conv_b = (const float*)d_in[4];
    float* out = (float*)d_out;
    char* ws = (char*)d_ws;

    unsigned short* x_t = (unsigned short*)(ws);
    unsigned short* cwt = (unsigned short*)(ws + CWT_OFF);
    unsigned short* pwt = (unsigned short*)(ws + PWT_OFF);

    k_prep_x<<<512, 256, 0, stream>>>(x, (unsigned int*)x_t);
    k_prep_w<<<216, 256, 0, stream>>>(conv_w, p_w, cwt, pwt);
    k_fused<<<1024, 256, 0, stream>>>(x_t, cwt, pwt, p_b, conv_b, out);
}